// Round 14
// baseline (190.700 us; speedup 1.0000x reference)
//
#include <hip/hip_runtime.h>
#include <hip/hip_bf16.h>

#define B_ 2
#define S_ 2048
#define D_ 1024
#define H_ 16
#define DKV_ 64
#define INNER_ 1024
#define M_ (B_*S_)   // 4096

typedef unsigned short ushort_t;
typedef unsigned int u32;
typedef __bf16 bf16x8 __attribute__((ext_vector_type(8)));
typedef __bf16 bf16x4 __attribute__((ext_vector_type(4)));
typedef float f32x4 __attribute__((ext_vector_type(4)));

#define VMCNT0 asm volatile("s_waitcnt vmcnt(0)" ::: "memory")
#define LOG2E 1.4426950408889634f

__device__ __forceinline__ unsigned short f2bf(float f) {
    unsigned int u = __builtin_bit_cast(unsigned int, f);
    unsigned int r = (u + 0x7fffu + ((u >> 16) & 1u)) >> 16;
    return (unsigned short)r;
}

__device__ __forceinline__ void gload16(const ushort_t* g, ushort_t* l) {
    __builtin_amdgcn_global_load_lds(
        (const __attribute__((address_space(1))) u32*)g,
        (__attribute__((address_space(3))) u32*)l, 16, 0, 0);
}

// ---------------- fused prep: cvt(hidden) + transpose(weights) + bias table ----------------
__global__ __launch_bounds__(256) void prep_kernel(
        const float* __restrict__ hs,
        const float* __restrict__ s0, const float* __restrict__ s1,
        const float* __restrict__ s2, const float* __restrict__ s3,
        const float* __restrict__ rb,
        unsigned short* __restrict__ Abf,
        unsigned short* __restrict__ d0, unsigned short* __restrict__ d1,
        unsigned short* __restrict__ d2, unsigned short* __restrict__ d3,
        float* __restrict__ btab) {
    int bid = blockIdx.x, tid = threadIdx.x;
    if (bid < 4096) {
        int i = (bid * 256 + tid) * 4;
        float4 v = *(const float4*)&hs[i];
        ushort4 o;
        o.x = f2bf(v.x); o.y = f2bf(v.y); o.z = f2bf(v.z); o.w = f2bf(v.w);
        *(ushort4*)&Abf[i] = o;
    } else if (bid < 5120) {
        int t = bid - 4096;
        int z = t >> 8, rem = t & 255;
        int k0 = ((rem >> 4) & 15) * 64, n0 = (rem & 15) * 64;
        const float* srcs[4] = {s0, s1, s2, s3};
        unsigned short* dsts[4] = {d0, d1, d2, d3};
        const float* src = srcs[z];
        unsigned short* dst = dsts[z];
        __shared__ float tbuf[64][65];
        for (int i = tid; i < 4096; i += 256) {
            int r = i >> 6, c = i & 63;
            tbuf[r][c] = src[(k0 + r) * 1024 + n0 + c];
        }
        __syncthreads();
        for (int i = tid; i < 4096; i += 256) {
            int r = i >> 6, c = i & 63;
            dst[(n0 + r) * 1024 + k0 + c] = f2bf(tbuf[c][r]);
        }
    } else {
        #pragma unroll
        for (int j = 0; j < 4; ++j) {
            int idx = (bid - 5120) * 1024 + j * 256 + tid;
            int h = idx >> 12, pos = idx & 4095;
            int rel = pos - 2048;
            int bb = rel > 0 ? 16 : 0;
            int rp = rel < 0 ? -rel : rel;
            int bucket;
            if (rp < 8) bucket = bb + rp;
            else {
                int v = 8 + (int)(logf((float)rp * 0.125f) / 2.7725887f * 8.0f);
                bucket = bb + (v < 15 ? v : 15);
            }
            btab[idx] = rb[bucket * 16 + h] * LOG2E;
        }
    }
}

// ---------------- fused QKV GEMM: A[4096][1024] x {WQ,WK,WV}^T, 128x128 tile, BK=64 ----------------
__global__ __launch_bounds__(256) void gemm_qkv(const ushort_t* __restrict__ A,
        const ushort_t* __restrict__ WQ, const ushort_t* __restrict__ WK, const ushort_t* __restrict__ WV,
        ushort_t* __restrict__ Qb, ushort_t* __restrict__ Kb, ushort_t* __restrict__ Vtb) {
    __shared__ alignas(16) ushort_t As[128][64];
    __shared__ alignas(16) ushort_t Bs[128][64];
    int tid = threadIdx.x, wid = tid >> 6, lane = tid & 63;
    int linear = blockIdx.x;                    // 768 blocks
    int swz = (linear & 7) * 96 + (linear >> 3);
    int m0 = (swz / 24) * 128;
    int nblk = swz % 24;
    int sel = nblk >> 3;                        // 0=Q 1=K 2=V
    const ushort_t* Bt = sel == 0 ? WQ : (sel == 1 ? WK : WV);
    int n0 = (nblk & 7) * 128;
    int lr = lane & 15, lg = lane >> 4;
    int wm = (wid >> 1) * 64, wn = (wid & 1) * 64;
    int srow = tid >> 3, sp = tid & 7;
    int scol = (sp ^ (srow & 7)) * 8;
    int cR0 = (lg ^ (lr & 7)) * 8;
    int cR1 = ((4 + lg) ^ (lr & 7)) * 8;
    const ushort_t* Abase = A + (size_t)m0 * 1024 + scol;
    const ushort_t* Bbase = Bt + (size_t)n0 * 1024 + scol;
    f32x4 acc[4][4] = {};
    for (int kt = 0; kt < 1024; kt += 64) {
        #pragma unroll
        for (int j = 0; j < 4; ++j) {
            int row = j * 32 + srow;
            gload16(Abase + row * 1024 + kt, &As[0][0] + (j * 256 + tid) * 8);
            gload16(Bbase + row * 1024 + kt, &Bs[0][0] + (j * 256 + tid) * 8);
        }
        VMCNT0;
        __syncthreads();
        bf16x8 af[4][2], bfr[4][2];
        #pragma unroll
        for (int t = 0; t < 4; ++t) {
            af[t][0]  = *(const bf16x8*)&As[wm + t * 16 + lr][cR0];
            af[t][1]  = *(const bf16x8*)&As[wm + t * 16 + lr][cR1];
            bfr[t][0] = *(const bf16x8*)&Bs[wn + t * 16 + lr][cR0];
            bfr[t][1] = *(const bf16x8*)&Bs[wn + t * 16 + lr][cR1];
        }
        #pragma unroll
        for (int hh = 0; hh < 2; ++hh)
            #pragma unroll
            for (int i2 = 0; i2 < 4; ++i2)
                #pragma unroll
                for (int j2 = 0; j2 < 4; ++j2)
                    acc[i2][j2] = __builtin_amdgcn_mfma_f32_16x16x32_bf16(af[i2][hh], bfr[j2][hh], acc[i2][j2], 0, 0, 0);
        __syncthreads();
    }
    #pragma unroll
    for (int i2 = 0; i2 < 4; ++i2)
        #pragma unroll
        for (int j2 = 0; j2 < 4; ++j2) {
            int col = n0 + wn + j2 * 16 + lr;
            int hh = col >> 6, d = col & 63;
            if (sel < 2) {
                ushort_t* dst = sel == 0 ? Qb : Kb;
                #pragma unroll
                for (int r = 0; r < 4; ++r) {
                    int row = m0 + wm + i2 * 16 + lg * 4 + r;
                    int b = row >> 11, s = row & 2047;
                    dst[(((size_t)(b * H_ + hh) * S_ + s)) * DKV_ + d] = f2bf(acc[i2][j2][r]);
                }
            } else {
                int row0 = m0 + wm + i2 * 16 + lg * 4;
                int b = row0 >> 11, s0 = row0 & 2047;
                ushort4 sv;
                sv.x = f2bf(acc[i2][j2][0]); sv.y = f2bf(acc[i2][j2][1]);
                sv.z = f2bf(acc[i2][j2][2]); sv.w = f2bf(acc[i2][j2][3]);
                *(ushort4*)&Vtb[((size_t)(b * H_ + hh) * DKV_ + d) * S_ + s0] = sv;
            }
        }
}

// ---------------- output projection GEMM: 64x128 tile, BK=64, fp32 out ----------------
__global__ __launch_bounds__(256) void gemm_out(const ushort_t* __restrict__ A,
                                                const ushort_t* __restrict__ Bt,
                                                float* __restrict__ C) {
    __shared__ alignas(16) ushort_t As[64][64];
    __shared__ alignas(16) ushort_t Bs[128][64];
    int tid = threadIdx.x, wid = tid >> 6, lane = tid & 63;
    int linear = blockIdx.x;                    // 512 blocks
    int swz = (linear & 7) * 64 + (linear >> 3);
    int m0 = (swz >> 3) * 64, n0 = (swz & 7) * 128;
    int lr = lane & 15, lg = lane >> 4;
    int wn = wid * 32;
    int srow = tid >> 3, sp = tid & 7;
    int scol = (sp ^ (srow & 7)) * 8;
    int cR0 = (lg ^ (lr & 7)) * 8;
    int cR1 = ((4 + lg) ^ (lr & 7)) * 8;
    const ushort_t* Abase = A + (size_t)m0 * 1024 + scol;
    const ushort_t* Bbase = Bt + (size_t)n0 * 1024 + scol;
    f32x4 acc[4][2] = {};
    for (int kt = 0; kt < 1024; kt += 64) {
        #pragma unroll
        for (int j = 0; j < 2; ++j) {
            int row = j * 32 + srow;
            gload16(Abase + row * 1024 + kt, &As[0][0] + (j * 256 + tid) * 8);
        }
        #pragma unroll
        for (int j = 0; j < 4; ++j) {
            int row = j * 32 + srow;
            gload16(Bbase + row * 1024 + kt, &Bs[0][0] + (j * 256 + tid) * 8);
        }
        VMCNT0;
        __syncthreads();
        bf16x8 af[4][2], bfr[2][2];
        #pragma unroll
        for (int t = 0; t < 4; ++t) {
            af[t][0] = *(const bf16x8*)&As[t * 16 + lr][cR0];
            af[t][1] = *(const bf16x8*)&As[t * 16 + lr][cR1];
        }
        #pragma unroll
        for (int j = 0; j < 2; ++j) {
            bfr[j][0] = *(const bf16x8*)&Bs[wn + j * 16 + lr][cR0];
            bfr[j][1] = *(const bf16x8*)&Bs[wn + j * 16 + lr][cR1];
        }
        #pragma unroll
        for (int hh = 0; hh < 2; ++hh)
            #pragma unroll
            for (int i2 = 0; i2 < 4; ++i2)
                #pragma unroll
                for (int j2 = 0; j2 < 2; ++j2)
                    acc[i2][j2] = __builtin_amdgcn_mfma_f32_16x16x32_bf16(af[i2][hh], bfr[j2][hh], acc[i2][j2], 0, 0, 0);
        __syncthreads();
    }
    #pragma unroll
    for (int i2 = 0; i2 < 4; ++i2)
        #pragma unroll
        for (int j2 = 0; j2 < 2; ++j2)
            #pragma unroll
            for (int r = 0; r < 4; ++r)
                C[(size_t)(m0 + i2 * 16 + lg * 4 + r) * 1024 + n0 + wn + j2 * 16 + lr] = acc[i2][j2][r];
}

// ---------------- flash attention v12: QBLK=64 (16 q/wave), 1024 blocks, one-ahead V regs,
//                  natural VGPR (no min-waves cap), race-free counted vmcnt(8) ----------------
__global__ __launch_bounds__(256) void flash_attn(const ushort_t* __restrict__ Q,
                                                  const ushort_t* __restrict__ Kg,
                                                  const ushort_t* __restrict__ Vt,
                                                  const float* __restrict__ bias_tab,
                                                  ushort_t* __restrict__ Out) {
    __shared__ alignas(16) ushort_t Ks[2][64][64];     // 16 KB
    __shared__ alignas(16) ushort_t Ps[4][16][64];     // 8 KB
    __shared__ float LbS[2112];                        // 8.25 KB
    int tid = threadIdx.x, wid = tid >> 6, lane = tid & 63;
    int linear = blockIdx.x;                 // 1024 blocks
    int swz = (linear & 7) * 128 + (linear >> 3);   // 4 bh per XCD slice
    int bh = swz >> 5, qblk = swz & 31;
    int h = bh & 15, b = bh >> 4;
    int q0b = qblk * 64;
    int q0w = q0b + wid * 16;                // this wave: 16 q rows
    int lr = lane & 15, lg = lane >> 4;

    // bias slice + saturated constants (pre-scaled by log2e)
    {
        const float* bsrc = bias_tab + h * 4096 + 2048 - q0b - 63;
        for (int i = tid; i < 2111; i += 256) LbS[i] = bsrc[i];
    }
    float cpos = bias_tab[h * 4096 + 4095];   // rel >= 128 (bucket 31)
    float cneg = bias_tab[h * 4096 + 0];      // rel <= -128 (bucket 15)

    // Q fragments
    const ushort_t* Qbase = Q + ((size_t)bh * S_ + q0w) * DKV_;
    bf16x8 qA0 = *(const bf16x8*)&Qbase[lr * DKV_ + lg * 8];
    bf16x8 qA1 = *(const bf16x8*)&Qbase[lr * DKV_ + 32 + lg * 8];

    // K staging geometry (pre-swizzled source)
    int srow = tid >> 3, sp = tid & 7;
    int kc = (sp ^ (srow & 7)) * 8;
    const ushort_t* Ksrc = Kg + (size_t)bh * S_ * DKV_ + kc;
    // V direct fragment base
    const ushort_t* Vfrag = Vt + ((size_t)bh * DKV_ + lr) * S_ + lg * 8;
    // swizzled K fragment-read columns
    int c0 = (lg ^ (lr & 7)) * 8;
    int c1 = ((4 + lg) ^ (lr & 7)) * 8;
    int pxor = (lr & 7) << 4;

    f32x4 oA[4] = {};
    f32x4 lpA = {};
    const int bbA = 63 - wid * 16 + 4 * lg - lr;

    auto stageK = [&](int bi, int kt) {
        ushort_t* kb = &Ks[bi][0][0];
        gload16(Ksrc + (size_t)(kt + srow) * 64,      kb + tid * 8);
        gload16(Ksrc + (size_t)(kt + 32 + srow) * 64, kb + 2048 + tid * 8);
    };
    auto loadV = [&](int kt, bf16x8 (&v)[4][2]) {
        #pragma unroll
        for (int dt = 0; dt < 4; ++dt) {
            const ushort_t* vp = Vfrag + (size_t)dt * 16 * S_ + kt;
            v[dt][0] = *(const bf16x8*)vp;
            v[dt][1] = *(const bf16x8*)(vp + 32);
        }
    };
    auto qk = [&](int buf, f32x4* sA) {
        __builtin_amdgcn_s_setprio(1);
        #pragma unroll
        for (int nt = 0; nt < 4; ++nt) {
            bf16x8 kf0 = *(const bf16x8*)&Ks[buf][nt * 16 + lr][c0];
            bf16x8 kf1 = *(const bf16x8*)&Ks[buf][nt * 16 + lr][c1];
            sA[nt] = __builtin_amdgcn_mfma_f32_16x16x32_bf16(kf0, qA0, sA[nt], 0, 0, 0);
            sA[nt] = __builtin_amdgcn_mfma_f32_16x16x32_bf16(kf1, qA1, sA[nt], 0, 0, 0);
        }
        __builtin_amdgcn_s_setprio(0);
    };
    // fixed-reference softmax (m = 0) + PV; pure per-lane VALU
    auto smpv = [&](f32x4 (&s)[4], f32x4& lp, f32x4 (&o)[4],
                    int bi, bool far, float cb, const bf16x8 (&vf)[4][2]) {
        float p[4][4];
        if (far) {
            #pragma unroll
            for (int nt = 0; nt < 4; ++nt)
                #pragma unroll
                for (int r = 0; r < 4; ++r)
                    p[nt][r] = __builtin_amdgcn_exp2f(fmaf(s[nt][r], LOG2E, cb));
        } else {
            #pragma unroll
            for (int nt = 0; nt < 4; ++nt)
                #pragma unroll
                for (int r = 0; r < 4; ++r)
                    p[nt][r] = __builtin_amdgcn_exp2f(fmaf(s[nt][r], LOG2E, LbS[bi + nt * 16 + r]));
        }
        char* pbase = (char*)&Ps[wid][lr][0];
        #pragma unroll
        for (int nt = 0; nt < 4; ++nt) {
            #pragma unroll
            for (int r = 0; r < 4; ++r) lp[r] += p[nt][r];
            bf16x4 pv;
            pv[0] = (__bf16)p[nt][0]; pv[1] = (__bf16)p[nt][1];
            pv[2] = (__bf16)p[nt][2]; pv[3] = (__bf16)p[nt][3];
            *(bf16x4*)(pbase + ((nt * 32 + lg * 8) ^ pxor)) = pv;
        }
        bf16x8 pf0 = *(const bf16x8*)(pbase + ((lg * 16) ^ pxor));
        bf16x8 pf1 = *(const bf16x8*)(pbase + ((64 + lg * 16) ^ pxor));
        __builtin_amdgcn_s_setprio(1);
        #pragma unroll
        for (int dt = 0; dt < 4; ++dt) {
            o[dt] = __builtin_amdgcn_mfma_f32_16x16x32_bf16(vf[dt][0], pf0, o[dt], 0, 0, 0);
            o[dt] = __builtin_amdgcn_mfma_f32_16x16x32_bf16(vf[dt][1], pf1, o[dt], 0, 0, 0);
        }
        __builtin_amdgcn_s_setprio(0);
    };

    bf16x8 vu[4][2], vn[4][2];
    f32x4 sCA[4] = {};

    // prologue: K(0),K(1) -> LDS FIRST (oldest in queue), then V(0) -> regs
    stageK(0, 0);
    stageK(1, 64);
    loadV(0, vu);
    asm volatile("s_waitcnt vmcnt(8) lgkmcnt(0)" ::: "memory");   // K(0),K(1) landed; V(0) may fly
    __builtin_amdgcn_s_barrier();
    __builtin_amdgcn_sched_barrier(0);
    qk(0, sCA);                               // QK(0)
    __builtin_amdgcn_s_barrier();             // all waves done reading Ks[0] before iter-0 restages it
    __builtin_amdgcn_sched_barrier(0);

    #pragma unroll 2
    for (int t = 0; t < 32; ++t) {
        const int kt = t * 64;
        const bool even = (t & 1) == 0;
        bf16x8 (&vuse)[4][2] = even ? vu : vn;
        bf16x8 (&vnxt)[4][2] = even ? vn : vu;
        // Issue K BEFORE V: K(t+2) is then older than V(t+1), so end-of-iter vmcnt(8)
        // (leaving only V(t+1) in flight) provably drains K(t+2) before next iter's qk.
        if (t < 30) stageK(t & 1, kt + 128);  // 2 global_load_lds
        if (t < 31) loadV(kt + 64, vnxt);     // 8 global_load_dwordx4 -> regs
        __builtin_amdgcn_sched_barrier(0);    // pin load issue point
        // QK(t+1): independent of softmax(t); K(t+1) guaranteed landed by prev iter's vmcnt(8)
        f32x4 sNA[4] = {};
        if (t < 31) qk((t + 1) & 1, sNA);
        // softmax(t) + PV(t)
        const bool far = (kt >= q0b + 192) || (kt + 64 <= q0b - 128);
        const float cb = (kt > q0b) ? cpos : cneg;
        smpv(sCA, lpA, oA, kt + bbA, far, cb, vuse);
        // hand off scores
        #pragma unroll
        for (int nt = 0; nt < 4; ++nt) sCA[nt] = sNA[nt];
        // end-of-iter: drain K(t+2) (and older), keep V(t+1) in flight
        if (t < 31) {
            asm volatile("s_waitcnt vmcnt(8)" ::: "memory");
            __builtin_amdgcn_s_barrier();
            __builtin_amdgcn_sched_barrier(0);
        }
    }

    // final cross-lane l reduction (4 lanes sharing lr)
    float lA = (lpA[0] + lpA[1]) + (lpA[2] + lpA[3]);
    lA += __shfl_xor(lA, 16); lA += __shfl_xor(lA, 32);
    // epilogue
    {
        float linv = 1.f / lA;
        char* pbase = (char*)&Ps[wid][lr][0];
        #pragma unroll
        for (int dt = 0; dt < 4; ++dt) {
            bf16x4 ov;
            ov[0] = (__bf16)(oA[dt][0] * linv); ov[1] = (__bf16)(oA[dt][1] * linv);
            ov[2] = (__bf16)(oA[dt][2] * linv); ov[3] = (__bf16)(oA[dt][3] * linv);
            *(bf16x4*)(pbase + ((dt * 32 + lg * 8) ^ pxor)) = ov;
        }
        int row = lane >> 2, seg = lane & 3;
        int rxor = (row & 7) << 4;
        char* rbase = (char*)&Ps[wid][row][0];
        uint4 v0 = *(uint4*)(rbase + ((seg * 32) ^ rxor));
        uint4 v1 = *(uint4*)(rbase + ((seg * 32 + 16) ^ rxor));
        ushort_t* dst = Out + (size_t)(b * S_ + q0w + row) * INNER_ + h * DKV_ + seg * 16;
        *(uint4*)&dst[0] = v0;
        *(uint4*)&dst[8] = v1;
    }
}

extern "C" void kernel_launch(void* const* d_in, const int* in_sizes, int n_in,
                              void* d_out, int out_size, void* d_ws, size_t ws_size,
                              hipStream_t stream) {
    const float* hs = (const float*)d_in[0];
    const float* wq = (const float*)d_in[1];
    const float* wk = (const float*)d_in[2];
    const float* wv = (const float*)d_in[3];
    const float* wo = (const float*)d_in[4];
    const float* rb = (const float*)d_in[5];

    char* ws = (char*)d_ws;
    unsigned short* Abf = (unsigned short*)(ws);                 // 8 MB  [4096][1024]
    unsigned short* Wqt = (unsigned short*)(ws + (8u  << 20));   // 2 MB  [1024][1024]
    unsigned short* Wkt = (unsigned short*)(ws + (10u << 20));
    unsigned short* Wvt = (unsigned short*)(ws + (12u << 20));
    unsigned short* Wot = (unsigned short*)(ws + (14u << 20));
    unsigned short* Qb  = (unsigned short*)(ws + (16u << 20));   // 8 MB  [b][h][s][64]
    unsigned short* Kb  = (unsigned short*)(ws + (24u << 20));   // 8 MB
    unsigned short* Vtb = (unsigned short*)(ws + (32u << 20));   // 8 MB  [b][h][64][s]
    unsigned short* AOb = (unsigned short*)(ws + (40u << 20));   // 8 MB  [4096][1024]
    float*          Btab = (float*)(ws + (48u << 20));           // 256 KB [16][4096]

    prep_kernel<<<5184, 256, 0, stream>>>(hs, wq, wk, wv, wo, rb,
                                          Abf, Wqt, Wkt, Wvt, Wot, Btab);

    gemm_qkv<<<768, 256, 0, stream>>>(Abf, Wqt, Wkt, Wvt, Qb, Kb, Vtb);

    flash_attn<<<1024, 256, 0, stream>>>(Qb, Kb, Vtb, Btab, AOb);

    gemm_out<<<512, 256, 0, stream>>>(AOb, Wot, (float*)d_out);
}

// Round 15
// 133.721 us; speedup vs baseline: 1.4261x; 1.4261x over previous
//
#include <hip/hip_runtime.h>
#include <hip/hip_bf16.h>

#define B_ 2
#define S_ 2048
#define D_ 1024
#define H_ 16
#define DKV_ 64
#define INNER_ 1024
#define M_ (B_*S_)   // 4096

typedef unsigned short ushort_t;
typedef unsigned int u32;
typedef __bf16 bf16x8 __attribute__((ext_vector_type(8)));
typedef __bf16 bf16x4 __attribute__((ext_vector_type(4)));
typedef float f32x4 __attribute__((ext_vector_type(4)));

#define VMCNT0 asm volatile("s_waitcnt vmcnt(0)" ::: "memory")
#define LOG2E 1.4426950408889634f

__device__ __forceinline__ unsigned short f2bf(float f) {
    unsigned int u = __builtin_bit_cast(unsigned int, f);
    unsigned int r = (u + 0x7fffu + ((u >> 16) & 1u)) >> 16;
    return (unsigned short)r;
}

__device__ __forceinline__ void gload16(const ushort_t* g, ushort_t* l) {
    __builtin_amdgcn_global_load_lds(
        (const __attribute__((address_space(1))) u32*)g,
        (__attribute__((address_space(3))) u32*)l, 16, 0, 0);
}

// ---------------- fused prep: cvt(hidden) + transpose(weights) + bias table ----------------
__global__ __launch_bounds__(256) void prep_kernel(
        const float* __restrict__ hs,
        const float* __restrict__ s0, const float* __restrict__ s1,
        const float* __restrict__ s2, const float* __restrict__ s3,
        const float* __restrict__ rb,
        unsigned short* __restrict__ Abf,
        unsigned short* __restrict__ d0, unsigned short* __restrict__ d1,
        unsigned short* __restrict__ d2, unsigned short* __restrict__ d3,
        float* __restrict__ btab) {
    int bid = blockIdx.x, tid = threadIdx.x;
    if (bid < 4096) {
        int i = (bid * 256 + tid) * 4;
        float4 v = *(const float4*)&hs[i];
        ushort4 o;
        o.x = f2bf(v.x); o.y = f2bf(v.y); o.z = f2bf(v.z); o.w = f2bf(v.w);
        *(ushort4*)&Abf[i] = o;
    } else if (bid < 5120) {
        int t = bid - 4096;
        int z = t >> 8, rem = t & 255;
        int k0 = ((rem >> 4) & 15) * 64, n0 = (rem & 15) * 64;
        const float* srcs[4] = {s0, s1, s2, s3};
        unsigned short* dsts[4] = {d0, d1, d2, d3};
        const float* src = srcs[z];
        unsigned short* dst = dsts[z];
        __shared__ float tbuf[64][65];
        for (int i = tid; i < 4096; i += 256) {
            int r = i >> 6, c = i & 63;
            tbuf[r][c] = src[(k0 + r) * 1024 + n0 + c];
        }
        __syncthreads();
        for (int i = tid; i < 4096; i += 256) {
            int r = i >> 6, c = i & 63;
            dst[(n0 + r) * 1024 + k0 + c] = f2bf(tbuf[c][r]);
        }
    } else {
        #pragma unroll
        for (int j = 0; j < 4; ++j) {
            int idx = (bid - 5120) * 1024 + j * 256 + tid;
            int h = idx >> 12, pos = idx & 4095;
            int rel = pos - 2048;
            int bb = rel > 0 ? 16 : 0;
            int rp = rel < 0 ? -rel : rel;
            int bucket;
            if (rp < 8) bucket = bb + rp;
            else {
                int v = 8 + (int)(logf((float)rp * 0.125f) / 2.7725887f * 8.0f);
                bucket = bb + (v < 15 ? v : 15);
            }
            btab[idx] = rb[bucket * 16 + h] * LOG2E;
        }
    }
}

// ---------------- fused QKV GEMM: A[4096][1024] x {WQ,WK,WV}^T, 128x128 tile, BK=64 ----------------
__global__ __launch_bounds__(256) void gemm_qkv(const ushort_t* __restrict__ A,
        const ushort_t* __restrict__ WQ, const ushort_t* __restrict__ WK, const ushort_t* __restrict__ WV,
        ushort_t* __restrict__ Qb, ushort_t* __restrict__ Kb, ushort_t* __restrict__ Vtb) {
    __shared__ alignas(16) ushort_t As[128][64];
    __shared__ alignas(16) ushort_t Bs[128][64];
    int tid = threadIdx.x, wid = tid >> 6, lane = tid & 63;
    int linear = blockIdx.x;                    // 768 blocks
    int swz = (linear & 7) * 96 + (linear >> 3);
    int m0 = (swz / 24) * 128;
    int nblk = swz % 24;
    int sel = nblk >> 3;                        // 0=Q 1=K 2=V
    const ushort_t* Bt = sel == 0 ? WQ : (sel == 1 ? WK : WV);
    int n0 = (nblk & 7) * 128;
    int lr = lane & 15, lg = lane >> 4;
    int wm = (wid >> 1) * 64, wn = (wid & 1) * 64;
    int srow = tid >> 3, sp = tid & 7;
    int scol = (sp ^ (srow & 7)) * 8;
    int cR0 = (lg ^ (lr & 7)) * 8;
    int cR1 = ((4 + lg) ^ (lr & 7)) * 8;
    const ushort_t* Abase = A + (size_t)m0 * 1024 + scol;
    const ushort_t* Bbase = Bt + (size_t)n0 * 1024 + scol;
    f32x4 acc[4][4] = {};
    for (int kt = 0; kt < 1024; kt += 64) {
        #pragma unroll
        for (int j = 0; j < 4; ++j) {
            int row = j * 32 + srow;
            gload16(Abase + row * 1024 + kt, &As[0][0] + (j * 256 + tid) * 8);
            gload16(Bbase + row * 1024 + kt, &Bs[0][0] + (j * 256 + tid) * 8);
        }
        VMCNT0;
        __syncthreads();
        bf16x8 af[4][2], bfr[4][2];
        #pragma unroll
        for (int t = 0; t < 4; ++t) {
            af[t][0]  = *(const bf16x8*)&As[wm + t * 16 + lr][cR0];
            af[t][1]  = *(const bf16x8*)&As[wm + t * 16 + lr][cR1];
            bfr[t][0] = *(const bf16x8*)&Bs[wn + t * 16 + lr][cR0];
            bfr[t][1] = *(const bf16x8*)&Bs[wn + t * 16 + lr][cR1];
        }
        #pragma unroll
        for (int hh = 0; hh < 2; ++hh)
            #pragma unroll
            for (int i2 = 0; i2 < 4; ++i2)
                #pragma unroll
                for (int j2 = 0; j2 < 4; ++j2)
                    acc[i2][j2] = __builtin_amdgcn_mfma_f32_16x16x32_bf16(af[i2][hh], bfr[j2][hh], acc[i2][j2], 0, 0, 0);
        __syncthreads();
    }
    #pragma unroll
    for (int i2 = 0; i2 < 4; ++i2)
        #pragma unroll
        for (int j2 = 0; j2 < 4; ++j2) {
            int col = n0 + wn + j2 * 16 + lr;
            int hh = col >> 6, d = col & 63;
            if (sel < 2) {
                ushort_t* dst = sel == 0 ? Qb : Kb;
                #pragma unroll
                for (int r = 0; r < 4; ++r) {
                    int row = m0 + wm + i2 * 16 + lg * 4 + r;
                    int b = row >> 11, s = row & 2047;
                    dst[(((size_t)(b * H_ + hh) * S_ + s)) * DKV_ + d] = f2bf(acc[i2][j2][r]);
                }
            } else {
                int row0 = m0 + wm + i2 * 16 + lg * 4;
                int b = row0 >> 11, s0 = row0 & 2047;
                ushort4 sv;
                sv.x = f2bf(acc[i2][j2][0]); sv.y = f2bf(acc[i2][j2][1]);
                sv.z = f2bf(acc[i2][j2][2]); sv.w = f2bf(acc[i2][j2][3]);
                *(ushort4*)&Vtb[((size_t)(b * H_ + hh) * DKV_ + d) * S_ + s0] = sv;
            }
        }
}

// ---------------- output projection GEMM: 64x128 tile, BK=64, fp32 out ----------------
__global__ __launch_bounds__(256) void gemm_out(const ushort_t* __restrict__ A,
                                                const ushort_t* __restrict__ Bt,
                                                float* __restrict__ C) {
    __shared__ alignas(16) ushort_t As[64][64];
    __shared__ alignas(16) ushort_t Bs[128][64];
    int tid = threadIdx.x, wid = tid >> 6, lane = tid & 63;
    int linear = blockIdx.x;                    // 512 blocks
    int swz = (linear & 7) * 64 + (linear >> 3);
    int m0 = (swz >> 3) * 64, n0 = (swz & 7) * 128;
    int lr = lane & 15, lg = lane >> 4;
    int wn = wid * 32;
    int srow = tid >> 3, sp = tid & 7;
    int scol = (sp ^ (srow & 7)) * 8;
    int cR0 = (lg ^ (lr & 7)) * 8;
    int cR1 = ((4 + lg) ^ (lr & 7)) * 8;
    const ushort_t* Abase = A + (size_t)m0 * 1024 + scol;
    const ushort_t* Bbase = Bt + (size_t)n0 * 1024 + scol;
    f32x4 acc[4][2] = {};
    for (int kt = 0; kt < 1024; kt += 64) {
        #pragma unroll
        for (int j = 0; j < 2; ++j) {
            int row = j * 32 + srow;
            gload16(Abase + row * 1024 + kt, &As[0][0] + (j * 256 + tid) * 8);
        }
        #pragma unroll
        for (int j = 0; j < 4; ++j) {
            int row = j * 32 + srow;
            gload16(Bbase + row * 1024 + kt, &Bs[0][0] + (j * 256 + tid) * 8);
        }
        VMCNT0;
        __syncthreads();
        bf16x8 af[4][2], bfr[2][2];
        #pragma unroll
        for (int t = 0; t < 4; ++t) {
            af[t][0] = *(const bf16x8*)&As[t * 16 + lr][cR0];
            af[t][1] = *(const bf16x8*)&As[t * 16 + lr][cR1];
        }
        #pragma unroll
        for (int j = 0; j < 2; ++j) {
            bfr[j][0] = *(const bf16x8*)&Bs[wn + j * 16 + lr][cR0];
            bfr[j][1] = *(const bf16x8*)&Bs[wn + j * 16 + lr][cR1];
        }
        #pragma unroll
        for (int hh = 0; hh < 2; ++hh)
            #pragma unroll
            for (int i2 = 0; i2 < 4; ++i2)
                #pragma unroll
                for (int j2 = 0; j2 < 2; ++j2)
                    acc[i2][j2] = __builtin_amdgcn_mfma_f32_16x16x32_bf16(af[i2][hh], bfr[j2][hh], acc[i2][j2], 0, 0, 0);
        __syncthreads();
    }
    #pragma unroll
    for (int i2 = 0; i2 < 4; ++i2)
        #pragma unroll
        for (int j2 = 0; j2 < 2; ++j2)
            #pragma unroll
            for (int r = 0; r < 4; ++r)
                C[(size_t)(m0 + i2 * 16 + lg * 4 + r) * 1024 + n0 + wn + j2 * 16 + lr] = acc[i2][j2][r];
}

// ---------------- flash attention v13: r9 base (QBLK=128, 2 q-groups, fixed-ref softmax,
//                  QK pipeline, V one-ahead regs) + Ks[3] 3-ahead race-free counted waits ----------------
__global__ __launch_bounds__(256, 2) void flash_attn(const ushort_t* __restrict__ Q,
                                                     const ushort_t* __restrict__ Kg,
                                                     const ushort_t* __restrict__ Vt,
                                                     const float* __restrict__ bias_tab,
                                                     ushort_t* __restrict__ Out) {
    __shared__ alignas(16) ushort_t Ks[3][64][64];     // 24 KB: buffer j holds K(t) with t%3==j
    __shared__ alignas(16) ushort_t Ps[4][16][64];     // 8 KB
    __shared__ float LbS[2176];                        // 8.5 KB
    int tid = threadIdx.x, wid = tid >> 6, lane = tid & 63;
    int linear = blockIdx.x;                 // 512 blocks
    int swz = (linear & 7) * 64 + (linear >> 3);
    int bh = swz >> 4, qblk = swz & 15;
    int h = bh & 15, b = bh >> 4;
    int q0b = qblk * 128;
    int q0w = q0b + wid * 32;                // this wave: q0w..q0w+31 (2 groups of 16)
    int lr = lane & 15, lg = lane >> 4;

    // bias slice + saturated constants (all pre-scaled by log2e)
    {
        const float* bsrc = bias_tab + h * 4096 + 2048 - q0b - 127;
        for (int i = tid; i < 2175; i += 256) LbS[i] = bsrc[i];
    }
    float cpos = bias_tab[h * 4096 + 4095];   // rel >= 128 (bucket 31)
    float cneg = bias_tab[h * 4096 + 0];      // rel <= -128 (bucket 15)

    // Q fragments, both groups
    const ushort_t* Qbase = Q + ((size_t)bh * S_ + q0w) * DKV_;
    bf16x8 qA0 = *(const bf16x8*)&Qbase[lr * DKV_ + lg * 8];
    bf16x8 qA1 = *(const bf16x8*)&Qbase[lr * DKV_ + 32 + lg * 8];
    bf16x8 qB0 = *(const bf16x8*)&Qbase[(16 + lr) * DKV_ + lg * 8];
    bf16x8 qB1 = *(const bf16x8*)&Qbase[(16 + lr) * DKV_ + 32 + lg * 8];

    // K staging geometry (pre-swizzled source)
    int srow = tid >> 3, sp = tid & 7;
    int kc = (sp ^ (srow & 7)) * 8;
    const ushort_t* Ksrc = Kg + (size_t)bh * S_ * DKV_ + kc;
    // V direct fragment base: row = bh*64 + dt*16 + lr, cols kt + lg*8 (+32)
    const ushort_t* Vfrag = Vt + ((size_t)bh * DKV_ + lr) * S_ + lg * 8;
    // swizzled K fragment-read columns
    int c0 = (lg ^ (lr & 7)) * 8;
    int c1 = ((4 + lg) ^ (lr & 7)) * 8;
    int pxor = (lr & 7) << 4;

    f32x4 oA[4] = {}, oB[4] = {};
    f32x4 lpA = {}, lpB = {};
    const int bbA = 127 - wid * 32 + 4 * lg - lr;
    const int bbB = bbA - 16;

    auto stageK = [&](int bi, int kt) {
        ushort_t* kb = &Ks[bi][0][0];
        gload16(Ksrc + (size_t)(kt + srow) * 64,      kb + tid * 8);
        gload16(Ksrc + (size_t)(kt + 32 + srow) * 64, kb + 2048 + tid * 8);
    };
    auto loadV = [&](int kt, bf16x8 (&v)[4][2]) {
        #pragma unroll
        for (int dt = 0; dt < 4; ++dt) {
            const ushort_t* vp = Vfrag + (size_t)dt * 16 * S_ + kt;
            v[dt][0] = *(const bf16x8*)vp;
            v[dt][1] = *(const bf16x8*)(vp + 32);
        }
    };
    auto qk = [&](int buf, f32x4* sA, f32x4* sB) {
        __builtin_amdgcn_s_setprio(1);
        #pragma unroll
        for (int nt = 0; nt < 4; ++nt) {
            bf16x8 kf0 = *(const bf16x8*)&Ks[buf][nt * 16 + lr][c0];
            bf16x8 kf1 = *(const bf16x8*)&Ks[buf][nt * 16 + lr][c1];
            sA[nt] = __builtin_amdgcn_mfma_f32_16x16x32_bf16(kf0, qA0, sA[nt], 0, 0, 0);
            sA[nt] = __builtin_amdgcn_mfma_f32_16x16x32_bf16(kf1, qA1, sA[nt], 0, 0, 0);
            sB[nt] = __builtin_amdgcn_mfma_f32_16x16x32_bf16(kf0, qB0, sB[nt], 0, 0, 0);
            sB[nt] = __builtin_amdgcn_mfma_f32_16x16x32_bf16(kf1, qB1, sB[nt], 0, 0, 0);
        }
        __builtin_amdgcn_s_setprio(0);
    };
    // fixed-reference softmax (m = 0) + PV; pure per-lane VALU, no cross-lane ops
    auto smpv = [&](f32x4 (&s)[4], f32x4& lp, f32x4 (&o)[4],
                    int bi, bool far, float cb, const bf16x8 (&vf)[4][2]) {
        float p[4][4];
        if (far) {
            #pragma unroll
            for (int nt = 0; nt < 4; ++nt)
                #pragma unroll
                for (int r = 0; r < 4; ++r)
                    p[nt][r] = __builtin_amdgcn_exp2f(fmaf(s[nt][r], LOG2E, cb));
        } else {
            #pragma unroll
            for (int nt = 0; nt < 4; ++nt)
                #pragma unroll
                for (int r = 0; r < 4; ++r)
                    p[nt][r] = __builtin_amdgcn_exp2f(fmaf(s[nt][r], LOG2E, LbS[bi + nt * 16 + r]));
        }
        char* pbase = (char*)&Ps[wid][lr][0];
        #pragma unroll
        for (int nt = 0; nt < 4; ++nt) {
            #pragma unroll
            for (int r = 0; r < 4; ++r) lp[r] += p[nt][r];
            bf16x4 pv;
            pv[0] = (__bf16)p[nt][0]; pv[1] = (__bf16)p[nt][1];
            pv[2] = (__bf16)p[nt][2]; pv[3] = (__bf16)p[nt][3];
            *(bf16x4*)(pbase + ((nt * 32 + lg * 8) ^ pxor)) = pv;
        }
        bf16x8 pf0 = *(const bf16x8*)(pbase + ((lg * 16) ^ pxor));
        bf16x8 pf1 = *(const bf16x8*)(pbase + ((64 + lg * 16) ^ pxor));
        __builtin_amdgcn_s_setprio(1);
        #pragma unroll
        for (int dt = 0; dt < 4; ++dt) {
            o[dt] = __builtin_amdgcn_mfma_f32_16x16x32_bf16(vf[dt][0], pf0, o[dt], 0, 0, 0);
            o[dt] = __builtin_amdgcn_mfma_f32_16x16x32_bf16(vf[dt][1], pf1, o[dt], 0, 0, 0);
        }
        __builtin_amdgcn_s_setprio(0);
    };

    bf16x8 vu[4][2], vn[4][2];
    f32x4 sCA[4] = {}, sCB[4] = {};

    // prologue: K(0),K(1),K(2) -> LDS; V(0) -> regs.
    // Outstanding after issues: K0(2) K1(2) K2(2) V0(8) = 14.
    stageK(0, 0);
    stageK(1, 64);
    stageK(2, 128);
    loadV(0, vu);
    asm volatile("s_waitcnt vmcnt(10) lgkmcnt(0)" ::: "memory");  // drain K0,K1 (K2+V0 = 10 newest fly)
    __builtin_amdgcn_s_barrier();
    __builtin_amdgcn_sched_barrier(0);
    qk(0, sCA, sCB);                          // QK(0); iter-0's qk(1) is covered by the same drain
    __builtin_amdgcn_s_barrier();             // all waves done reading Ks[0] before iter-0 restages it
    __builtin_amdgcn_sched_barrier(0);

    #pragma unroll 2
    for (int t = 0; t < 32; ++t) {
        const int kt = t * 64;
        const bool even = (t & 1) == 0;
        bf16x8 (&vuse)[4][2] = even ? vu : vn;
        bf16x8 (&vnxt)[4][2] = even ? vn : vu;
        // stage K(t+3) into buffer t%3 (holds dead K(t); all waves passed prior barrier)
        if (t <= 28) stageK(t % 3, kt + 192);
        if (t < 31) loadV(kt + 64, vnxt);
        __builtin_amdgcn_sched_barrier(0);    // pin load issue point
        // QK(t+1): reads K(t+1), staged at iter t-2, drained by iter t-1's end vmcnt(10)
        f32x4 sNA[4] = {}, sNB[4] = {};
        if (t < 31) {
            int nb = (t + 1) % 3;
            qk(nb, sNA, sNB);
        }
        // softmax(t) + PV(t)
        const bool far = (kt >= q0b + 256) || (kt + 64 <= q0b - 128);
        const float cb = (kt > q0b) ? cpos : cneg;
        smpv(sCA, lpA, oA, kt + bbA, far, cb, vuse);
        smpv(sCB, lpB, oB, kt + bbB, far, cb, vuse);
        // hand off scores
        #pragma unroll
        for (int nt = 0; nt < 4; ++nt) { sCA[nt] = sNA[nt]; sCB[nt] = sNB[nt]; }
        // end-of-iter: drain K(t+2) (needed by next iter's qk). 10 newest = K(t+3)(2)+V(t+1)(8).
        if (t < 31) {
            if (t <= 28) { asm volatile("s_waitcnt vmcnt(10)" ::: "memory"); }
            else         { asm volatile("s_waitcnt vmcnt(8)"  ::: "memory"); }  // no K staged this iter
            __builtin_amdgcn_s_barrier();
            __builtin_amdgcn_sched_barrier(0);
        }
    }

    // final cross-lane l reduction (4 lanes sharing lr)
    float lA = (lpA[0] + lpA[1]) + (lpA[2] + lpA[3]);
    lA += __shfl_xor(lA, 16); lA += __shfl_xor(lA, 32);
    float lB = (lpB[0] + lpB[1]) + (lpB[2] + lpB[3]);
    lB += __shfl_xor(lB, 16); lB += __shfl_xor(lB, 32);
    // epilogue group A
    {
        float linv = 1.f / lA;
        char* pbase = (char*)&Ps[wid][lr][0];
        #pragma unroll
        for (int dt = 0; dt < 4; ++dt) {
            bf16x4 ov;
            ov[0] = (__bf16)(oA[dt][0] * linv); ov[1] = (__bf16)(oA[dt][1] * linv);
            ov[2] = (__bf16)(oA[dt][2] * linv); ov[3] = (__bf16)(oA[dt][3] * linv);
            *(bf16x4*)(pbase + ((dt * 32 + lg * 8) ^ pxor)) = ov;
        }
        int row = lane >> 2, seg = lane & 3;
        int rxor = (row & 7) << 4;
        char* rbase = (char*)&Ps[wid][row][0];
        uint4 v0 = *(uint4*)(rbase + ((seg * 32) ^ rxor));
        uint4 v1 = *(uint4*)(rbase + ((seg * 32 + 16) ^ rxor));
        ushort_t* dst = Out + (size_t)(b * S_ + q0w + row) * INNER_ + h * DKV_ + seg * 16;
        *(uint4*)&dst[0] = v0;
        *(uint4*)&dst[8] = v1;
    }
    // epilogue group B
    {
        float linv = 1.f / lB;
        char* pbase = (char*)&Ps[wid][lr][0];
        #pragma unroll
        for (int dt = 0; dt < 4; ++dt) {
            bf16x4 ov;
            ov[0] = (__bf16)(oB[dt][0] * linv); ov[1] = (__bf16)(oB[dt][1] * linv);
            ov[2] = (__bf16)(oB[dt][2] * linv); ov[3] = (__bf16)(oB[dt][3] * linv);
            *(bf16x4*)(pbase + ((dt * 32 + lg * 8) ^ pxor)) = ov;
        }
        int row = lane >> 2, seg = lane & 3;
        int rxor = (row & 7) << 4;
        char* rbase = (char*)&Ps[wid][row][0];
        uint4 v0 = *(uint4*)(rbase + ((seg * 32) ^ rxor));
        uint4 v1 = *(uint4*)(rbase + ((seg * 32 + 16) ^ rxor));
        ushort_t* dst = Out + (size_t)(b * S_ + q0w + 16 + row) * INNER_ + h * DKV_ + seg * 16;
        *(uint4*)&dst[0] = v0;
        *(uint4*)&dst[8] = v1;
    }
}

extern "C" void kernel_launch(void* const* d_in, const int* in_sizes, int n_in,
                              void* d_out, int out_size, void* d_ws, size_t ws_size,
                              hipStream_t stream) {
    const float* hs = (const float*)d_in[0];
    const float* wq = (const float*)d_in[1];
    const float* wk = (const float*)d_in[2];
    const float* wv = (const float*)d_in[3];
    const float* wo = (const float*)d_in[4];
    const float* rb = (const float*)d_in[5];

    char* ws = (char*)d_ws;
    unsigned short* Abf = (unsigned short*)(ws);                 // 8 MB  [4096][1024]
    unsigned short* Wqt = (unsigned short*)(ws + (8u  << 20));   // 2 MB  [1024][1024]
    unsigned short* Wkt = (unsigned short*)(ws + (10u << 20));
    unsigned short* Wvt = (unsigned short*)(ws + (12u << 20));
    unsigned short* Wot = (unsigned short*)(ws + (14u << 20));
    unsigned short* Qb  = (unsigned short*)(ws + (16u << 20));   // 8 MB  [b][h][s][64]
    unsigned short* Kb  = (unsigned short*)(ws + (24u << 20));   // 8 MB
    unsigned short* Vtb = (unsigned short*)(ws + (32u << 20));   // 8 MB  [b][h][64][s]
    unsigned short* AOb = (unsigned short*)(ws + (40u << 20));   // 8 MB  [4096][1024]
    float*          Btab = (float*)(ws + (48u << 20));           // 256 KB [16][4096]

    prep_kernel<<<5184, 256, 0, stream>>>(hs, wq, wk, wv, wo, rb,
                                          Abf, Wqt, Wkt, Wvt, Wot, Btab);

    gemm_qkv<<<768, 256, 0, stream>>>(Abf, Wqt, Wkt, Wvt, Qb, Kb, Vtb);

    flash_attn<<<512, 256, 0, stream>>>(Qb, Kb, Vtb, Btab, AOb);

    gemm_out<<<512, 256, 0, stream>>>(AOb, Wot, (float*)d_out);
}